// Round 3
// baseline (114.039 us; speedup 1.0000x reference)
//
#include <hip/hip_runtime.h>

namespace {

constexpr int NB = 4096;                       // histogram bins
constexpr float HIST_MAX = 8.0f;               // |detail| range covered exactly
constexpr float INV_BINW = (float)NB / HIST_MAX;   // 512
constexpr float BINW = HIST_MAX / (float)NB;       // 1/512
constexpr float VSCALE = 65536.0f;             // fixed-point scale for value sums
constexpr float INV_VSCALE = 1.0f / 65536.0f;

// ws layout (bytes from base):
//   LL1  : 0          .. 33554432   (32*512*512 f32)
//   LL2  : 33554432   .. 41943040   (32*256*256 f32)
//   cnt  : 41943040   .. 43515904   (3 levels * 32 batches * 4096 u32)
//   vsum : 43515904   .. 46661632   (3 * 32 * 4096 u64)
//   sigma: 46661632   (32 f32)
//   loss : 46661760   (32 f32)
constexpr size_t OFF_LL1 = 0;
constexpr size_t OFF_LL2 = 33554432;
constexpr size_t OFF_CNT = 41943040;
constexpr size_t OFF_VSUM = 43515904;
constexpr size_t OFF_SIGMA = 46661632;
constexpr size_t OFF_LOSS = 46661760;

__device__ __forceinline__ void binval(float av, unsigned* scnt, unsigned* ssum) {
    int k = (int)(av * INV_BINW);
    k = k < NB - 1 ? k : NB - 1;
    atomicAdd(&scnt[k], 1u);
    atomicAdd(&ssum[k], (unsigned)(av * VSCALE));
}

// One Haar DWT level: src [B][2*Ho][Ws] -> dst(LL) [B][Ho][Ws/2] (optional),
// and per-batch histogram (count + value-sum) of |LH|,|HL|,|HH|.
__global__ __launch_bounds__(256) void k_dwt(
    const float* __restrict__ src, float* __restrict__ dst,
    unsigned* __restrict__ gcnt, unsigned long long* __restrict__ gsum,
    int Ws, int Ho, int rshift /* log2(Wo/2) */)
{
    __shared__ unsigned scnt[NB];
    __shared__ unsigned ssum[NB];
    for (int i = threadIdx.x; i < NB; i += 256) { scnt[i] = 0u; ssum[i] = 0u; }
    __syncthreads();

    const int b = blockIdx.y;
    const int Wo = Ws >> 1;
    const int ppr = Wo >> 1;              // float4 pairs per output row
    const int npairs = Ho * ppr;
    const float* sb = src + (size_t)b * (size_t)Ws * (size_t)(Ho * 2);
    float* db = dst ? dst + (size_t)b * (size_t)Wo * (size_t)Ho : nullptr;
    const int stride = gridDim.x * 256;

    for (int p = blockIdx.x * 256 + threadIdx.x; p < npairs; p += stride) {
        const int oy = p >> rshift;
        const int ox = p - (oy << rshift);
        const float* r0p = sb + (size_t)(2 * oy) * Ws + 4 * ox;
        const float4 r0 = *reinterpret_cast<const float4*>(r0p);
        const float4 r1 = *reinterpret_cast<const float4*>(r0p + Ws);
        // pos 0: a=r0.x b=r0.y c=r1.x d=r1.y ; pos 1: a=r0.z b=r0.w c=r1.z d=r1.w
        const float sab0 = r0.x + r0.y, dab0 = r0.x - r0.y;
        const float scd0 = r1.x + r1.y, dcd0 = r1.x - r1.y;
        const float sab1 = r0.z + r0.w, dab1 = r0.z - r0.w;
        const float scd1 = r1.z + r1.w, dcd1 = r1.z - r1.w;
        if (db) {
            *reinterpret_cast<float2*>(db + (size_t)oy * Wo + 2 * ox) =
                make_float2(0.5f * (sab0 + scd0), 0.5f * (sab1 + scd1));
        }
        binval(fabsf(0.5f * (sab0 - scd0)), scnt, ssum);  // LH
        binval(fabsf(0.5f * (dab0 + dcd0)), scnt, ssum);  // HL
        binval(fabsf(0.5f * (dab0 - dcd0)), scnt, ssum);  // HH
        binval(fabsf(0.5f * (sab1 - scd1)), scnt, ssum);
        binval(fabsf(0.5f * (dab1 + dcd1)), scnt, ssum);
        binval(fabsf(0.5f * (dab1 - dcd1)), scnt, ssum);
    }
    __syncthreads();
    unsigned* gc = gcnt + (size_t)b * NB;
    unsigned long long* gs = gsum + (size_t)b * NB;
    for (int i = threadIdx.x; i < NB; i += 256) {
        const unsigned c = scnt[i];
        if (c) {
            atomicAdd(&gc[i], c);
            atomicAdd(&gs[i], (unsigned long long)ssum[i]);
        }
    }
}

// sum of min(|x|, t) over one histogram bin, linear interp in straddle bin
__device__ __forceinline__ float contrib(unsigned c, float vs, int k, float t) {
    if (!c) return 0.0f;
    const float lo = (float)k * BINW;
    if (t >= lo + BINW) return vs;
    if (t <= lo) return t * (float)c;
    const float f = (t - lo) * INV_BINW;
    const float below = f * (float)c;
    return below * 0.5f * (lo + t) + ((float)c - below) * t;
}

__global__ __launch_bounds__(256) void k_stats(
    const unsigned* __restrict__ cnt, const unsigned long long* __restrict__ vsum,
    float* __restrict__ sigma_arr, float* __restrict__ loss_arr)
{
    const int b = blockIdx.x;
    const int tid = threadIdx.x;
    const unsigned* c1 = cnt + (size_t)b * NB;
    const unsigned* c2 = cnt + (size_t)(32 + b) * NB;
    const unsigned* c3 = cnt + (size_t)(64 + b) * NB;
    const unsigned long long* s1 = vsum + (size_t)b * NB;
    const unsigned long long* s2 = vsum + (size_t)(32 + b) * NB;
    const unsigned long long* s3 = vsum + (size_t)(64 + b) * NB;

    __shared__ unsigned csum[256];
    __shared__ float sh_t;
    // chunk sums for rank selection on level-1 counts
    unsigned local = 0;
    const int base = tid * (NB / 256);
    #pragma unroll
    for (int i = 0; i < NB / 256; ++i) local += c1[base + i];
    csum[tid] = local;
    __syncthreads();

    if (tid == 0) {
        // N = 3*512*512 = 786432 (even): median = avg of ranks 393216, 393217 (1-indexed)
        float vv[2];
        for (int q = 0; q < 2; ++q) {
            const long long r = 393216 + q;
            long long cum = 0;
            int ch = 0;
            while (ch < 255 && cum + (long long)csum[ch] < r) { cum += csum[ch]; ++ch; }
            int k = ch * (NB / 256);
            const int kend = k + NB / 256 - 1;
            while (k < kend && cum + (long long)c1[k] < r) { cum += c1[k]; ++k; }
            const unsigned cc = c1[k];
            float frac = cc ? ((float)(r - cum) - 0.5f) / (float)cc : 0.5f;
            frac = fminf(fmaxf(frac, 0.0f), 1.0f);
            vv[q] = ((float)k + frac) * BINW;
        }
        const float med = 0.5f * (vv[0] + vv[1]);
        const float sg = med * (1.0f / 0.6745f);
        sigma_arr[b] = sg;
        sh_t = fminf(fmaxf(sg * 2.5f, 0.05f), 0.3f);  // clip(2.5*sigma, 0.05, 0.3)
    }
    __syncthreads();
    const float t = sh_t;

    constexpr float coef1 = 1.0f / (3.0f * 8388608.0f);   // 1/(3*1*B*512*512)
    constexpr float coef2 = 1.0f / (6.0f * 2097152.0f);   // 1/(3*2*B*256*256)
    constexpr float coef3 = 1.0f / (9.0f * 524288.0f);    // 1/(3*3*B*128*128)
    float part = 0.0f;
    for (int i = tid; i < NB; i += 256) {
        part += coef1 * contrib(c1[i], (float)s1[i] * INV_VSCALE, i, t);
        part += coef2 * contrib(c2[i], (float)s2[i] * INV_VSCALE, i, t * 0.5f);
        part += coef3 * contrib(c3[i], (float)s3[i] * INV_VSCALE, i, t * 0.25f);
    }
    for (int off = 32; off; off >>= 1) part += __shfl_down(part, off, 64);
    __shared__ float wred[4];
    if ((tid & 63) == 0) wred[tid >> 6] = part;
    __syncthreads();
    if (tid == 0) loss_arr[b] = wred[0] + wred[1] + wred[2] + wred[3];
}

__global__ void k_final(const float* __restrict__ sigma_arr,
                        const float* __restrict__ loss_arr,
                        float* __restrict__ out)
{
    if (threadIdx.x == 0 && blockIdx.x == 0) {
        float ls = 0.0f, ss = 0.0f;
        for (int i = 0; i < 32; ++i) { ls += loss_arr[i]; ss += sigma_arr[i]; }
        out[0] = ls;                  // total_loss
        out[1] = ss * (1.0f / 32.0f); // avg_noise = mean(sigma)
    }
}

} // namespace

extern "C" void kernel_launch(void* const* d_in, const int* in_sizes, int n_in,
                              void* d_out, int out_size, void* d_ws, size_t ws_size,
                              hipStream_t stream) {
    const float* pred = (const float*)d_in[0];   // [32,1,1024,1024] f32
    float* out = (float*)d_out;                  // [total_loss, avg_noise]
    char* ws = (char*)d_ws;

    float* LL1 = (float*)(ws + OFF_LL1);
    float* LL2 = (float*)(ws + OFF_LL2);
    unsigned* cnt = (unsigned*)(ws + OFF_CNT);
    unsigned long long* vsum = (unsigned long long*)(ws + OFF_VSUM);
    float* sigma_arr = (float*)(ws + OFF_SIGMA);
    float* loss_arr = (float*)(ws + OFF_LOSS);

    // zero the histogram region (cnt + vsum are contiguous)
    (void)hipMemsetAsync(cnt, 0, (OFF_VSUM - OFF_CNT) + 3ull * 32 * NB * 8, stream);

    // Level 1: pred(1024x1024) -> LL1(512x512), hist set 0
    k_dwt<<<dim3(32, 32), 256, 0, stream>>>(pred, LL1, cnt, vsum, 1024, 512, 8);
    // Level 2: LL1(512x512) -> LL2(256x256), hist set 1
    k_dwt<<<dim3(16, 32), 256, 0, stream>>>(LL1, LL2, cnt + 32 * NB, vsum + 32 * NB, 512, 256, 7);
    // Level 3: LL2(256x256) -> (no LL3 needed), hist set 2
    k_dwt<<<dim3(8, 32), 256, 0, stream>>>(LL2, nullptr, cnt + 64 * NB, vsum + 64 * NB, 256, 128, 6);
    // Per-batch median -> sigma/threshold -> per-batch loss, all from histograms
    k_stats<<<32, 256, 0, stream>>>(cnt, vsum, sigma_arr, loss_arr);
    // Final scalars
    k_final<<<1, 64, 0, stream>>>(sigma_arr, loss_arr, out);
}

// Round 6
// 61.637 us; speedup vs baseline: 1.8502x; 1.8502x over previous
//
#include <hip/hip_runtime.h>

namespace {

constexpr int NB = 2048;                    // histogram bins per level
constexpr float INV_BINW = 256.0f;          // bins cover [0, 8)
constexpr float BINW = 1.0f / 256.0f;

// ws layout: cnt [3 levels][32 batches][NB] u32, then sigma[32], loss[32]
constexpr size_t OFF_CNT = 0;
constexpr size_t CNT_ELEMS = 3ull * 32 * NB;          // 196608
constexpr size_t OFF_SIGMA = CNT_ELEMS * 4;           // 786432
constexpr size_t OFF_LOSS = OFF_SIGMA + 128;

__device__ __forceinline__ void bump(unsigned* h, float av) {
    int k = (int)(av * INV_BINW);
    k = k < NB - 1 ? k : NB - 1;
    atomicAdd(&h[k], 1u);
}

__global__ __launch_bounds__(256) void k_zero(unsigned* __restrict__ cnt) {
    const int i = blockIdx.x * 256 + threadIdx.x;     // 49152 uint4 stores
    reinterpret_cast<uint4*>(cnt)[i] = make_uint4(0u, 0u, 0u, 0u);
}

// Fused 3-level Haar on disjoint 8x8 tiles; per-batch count histograms of
// |LH|,|HL|,|HH| at each level. src [32][1024][1024] f32.
__global__ __launch_bounds__(256) void k_fused(
    const float* __restrict__ src, unsigned* __restrict__ gcnt)
{
    __shared__ unsigned h[3 * NB];                    // 24 KB
    for (int i = threadIdx.x; i < 3 * NB; i += 256) h[i] = 0u;
    __syncthreads();

    const int b = blockIdx.y;
    const int tI = blockIdx.x * 256 + threadIdx.x;    // 16384 tiles/batch
    const int ty = tI >> 7;                           // 128 tiles per row
    const int tx = tI & 127;
    const float* base = src + (size_t)b * 1048576 + (size_t)ty * 8192 + (size_t)tx * 8;

    // load full 8x8 tile: 16 independent float4 loads (deep memory ILP)
    float4 R[16];
    #pragma unroll
    for (int r = 0; r < 8; ++r) {
        R[2 * r]     = *reinterpret_cast<const float4*>(base + (size_t)r * 1024);
        R[2 * r + 1] = *reinterpret_cast<const float4*>(base + (size_t)r * 1024 + 4);
    }

    // level 1: 16 2x2 blocks -> ll1[4][4] + 48 details
    float ll1[16];
    #pragma unroll
    for (int i = 0; i < 4; ++i) {           // output row (input row-pair 2i,2i+1)
        #pragma unroll
        for (int j = 0; j < 2; ++j) {       // float4 part (cols 0-3 / 4-7)
            const float4 t = R[4 * i + j];
            const float4 u = R[4 * i + 2 + j];
            const float sab0 = t.x + t.y, dab0 = t.x - t.y;
            const float scd0 = u.x + u.y, dcd0 = u.x - u.y;
            ll1[4 * i + 2 * j] = 0.5f * (sab0 + scd0);
            bump(h, fabsf(0.5f * (sab0 - scd0)));   // LH
            bump(h, fabsf(0.5f * (dab0 + dcd0)));   // HL
            bump(h, fabsf(0.5f * (dab0 - dcd0)));   // HH
            const float sab1 = t.z + t.w, dab1 = t.z - t.w;
            const float scd1 = u.z + u.w, dcd1 = u.z - u.w;
            ll1[4 * i + 2 * j + 1] = 0.5f * (sab1 + scd1);
            bump(h, fabsf(0.5f * (sab1 - scd1)));
            bump(h, fabsf(0.5f * (dab1 + dcd1)));
            bump(h, fabsf(0.5f * (dab1 - dcd1)));
        }
    }

    // level 2: ll1 4x4 -> ll2[2][2] + 12 details
    float ll2[4];
    #pragma unroll
    for (int i = 0; i < 2; ++i) {
        #pragma unroll
        for (int j = 0; j < 2; ++j) {
            const float a = ll1[8 * i + 2 * j];
            const float bb = ll1[8 * i + 2 * j + 1];
            const float c = ll1[8 * i + 4 + 2 * j];
            const float d = ll1[8 * i + 4 + 2 * j + 1];
            const float sab = a + bb, dab = a - bb;
            const float scd = c + d, dcd = c - d;
            ll2[2 * i + j] = 0.5f * (sab + scd);
            bump(h + NB, fabsf(0.5f * (sab - scd)));
            bump(h + NB, fabsf(0.5f * (dab + dcd)));
            bump(h + NB, fabsf(0.5f * (dab - dcd)));
        }
    }

    // level 3: ll2 2x2 -> 3 details
    {
        const float sab = ll2[0] + ll2[1], dab = ll2[0] - ll2[1];
        const float scd = ll2[2] + ll2[3], dcd = ll2[2] - ll2[3];
        bump(h + 2 * NB, fabsf(0.5f * (sab - scd)));
        bump(h + 2 * NB, fabsf(0.5f * (dab + dcd)));
        bump(h + 2 * NB, fabsf(0.5f * (dab - dcd)));
    }

    __syncthreads();
    // merge into global [level][batch][NB]
    for (int i = threadIdx.x; i < 3 * NB; i += 256) {
        const unsigned c = h[i];
        if (c) {
            const int lvl = i >> 11;          // i / NB
            const int bin = i & (NB - 1);
            atomicAdd(&gcnt[(size_t)lvl * 32 * NB + (size_t)b * NB + bin], c);
        }
    }
}

// sum of min(|x|, t) over one bin from count only (midpoint / uniform interp)
__device__ __forceinline__ float contrib(unsigned c, int k, float t) {
    if (!c) return 0.0f;
    const float lo = (float)k * BINW;
    if (t >= lo + BINW) return (float)c * (lo + 0.5f * BINW);
    if (t <= lo) return t * (float)c;
    const float f = (t - lo) * INV_BINW;
    const float below = f * (float)c;
    return below * 0.5f * (lo + t) + ((float)c - below) * t;
}

__global__ __launch_bounds__(256) void k_stats(
    const unsigned* __restrict__ cnt,
    float* __restrict__ sigma_arr, float* __restrict__ loss_arr)
{
    const int b = blockIdx.x;
    const int tid = threadIdx.x;
    const unsigned* c1 = cnt + (size_t)b * NB;
    const unsigned* c2 = cnt + (size_t)(32 + b) * NB;
    const unsigned* c3 = cnt + (size_t)(64 + b) * NB;

    __shared__ unsigned csum[256];
    __shared__ float sh_t;
    unsigned local = 0;
    const int base = tid * (NB / 256);
    #pragma unroll
    for (int i = 0; i < NB / 256; ++i) local += c1[base + i];
    csum[tid] = local;
    __syncthreads();

    if (tid == 0) {
        // N = 3*512*512 = 786432 even: median = avg of ranks 393216, 393217
        float vv[2];
        for (int q = 0; q < 2; ++q) {
            const long long r = 393216 + q;
            long long cum = 0;
            int ch = 0;
            while (ch < 255 && cum + (long long)csum[ch] < r) { cum += csum[ch]; ++ch; }
            int k = ch * (NB / 256);
            const int kend = k + NB / 256 - 1;
            while (k < kend && cum + (long long)c1[k] < r) { cum += c1[k]; ++k; }
            const unsigned cc = c1[k];
            float frac = cc ? ((float)(r - cum) - 0.5f) / (float)cc : 0.5f;
            frac = fminf(fmaxf(frac, 0.0f), 1.0f);
            vv[q] = ((float)k + frac) * BINW;
        }
        const float med = 0.5f * (vv[0] + vv[1]);
        const float sg = med * (1.0f / 0.6745f);
        sigma_arr[b] = sg;
        sh_t = fminf(fmaxf(sg * 2.5f, 0.05f), 0.3f);   // clip(2.5σ, 0.05, 0.3)
    }
    __syncthreads();
    const float t = sh_t;

    constexpr float coef1 = 1.0f / (3.0f * 8388608.0f);   // 1/(3*1*B*512*512)
    constexpr float coef2 = 1.0f / (6.0f * 2097152.0f);   // 1/(3*2*B*256*256)
    constexpr float coef3 = 1.0f / (9.0f * 524288.0f);    // 1/(3*3*B*128*128)
    float part = 0.0f;
    for (int i = tid; i < NB; i += 256) {
        part += coef1 * contrib(c1[i], i, t);
        part += coef2 * contrib(c2[i], i, t * 0.5f);
        part += coef3 * contrib(c3[i], i, t * 0.25f);
    }
    for (int off = 32; off; off >>= 1) part += __shfl_down(part, off, 64);
    __shared__ float wred[4];
    if ((tid & 63) == 0) wred[tid >> 6] = part;
    __syncthreads();
    if (tid == 0) loss_arr[b] = wred[0] + wred[1] + wred[2] + wred[3];
}

__global__ void k_final(const float* __restrict__ sigma_arr,
                        const float* __restrict__ loss_arr,
                        float* __restrict__ out)
{
    if (threadIdx.x == 0 && blockIdx.x == 0) {
        float ls = 0.0f, ss = 0.0f;
        for (int i = 0; i < 32; ++i) { ls += loss_arr[i]; ss += sigma_arr[i]; }
        out[0] = ls;                  // total_loss
        out[1] = ss * (1.0f / 32.0f); // avg_noise
    }
}

} // namespace

extern "C" void kernel_launch(void* const* d_in, const int* in_sizes, int n_in,
                              void* d_out, int out_size, void* d_ws, size_t ws_size,
                              hipStream_t stream) {
    const float* pred = (const float*)d_in[0];   // [32,1,1024,1024] f32
    float* out = (float*)d_out;                  // [total_loss, avg_noise]
    char* ws = (char*)d_ws;

    unsigned* cnt = (unsigned*)(ws + OFF_CNT);
    float* sigma_arr = (float*)(ws + OFF_SIGMA);
    float* loss_arr = (float*)(ws + OFF_LOSS);

    // zero 786 KB of histograms: 49152 uint4 / 256 = 192 blocks
    k_zero<<<192, 256, 0, stream>>>(cnt);
    // fused 3-level DWT + histograms: 64 blocks x 32 batches, 1 tile/thread
    k_fused<<<dim3(64, 32), 256, 0, stream>>>(pred, cnt);
    // per-batch median -> sigma -> threshold -> loss
    k_stats<<<32, 256, 0, stream>>>(cnt, sigma_arr, loss_arr);
    // final scalars
    k_final<<<1, 64, 0, stream>>>(sigma_arr, loss_arr, out);
}

// Round 7
// 52.064 us; speedup vs baseline: 2.1903x; 1.1839x over previous
//
#include <hip/hip_runtime.h>

namespace {

constexpr int NB = 512;                     // bins cover [0, 2): binw = 1/256
constexpr float BIN_SCALE = 128.0f;         // bin = |2*detail| * 128 = |detail| * 256
constexpr float INV_BINW = 256.0f;
constexpr float BINW = 1.0f / 256.0f;

// ws layout: cnt [3 levels][32 batches][NB] u32 (192 KB), then sigma[32], loss[32]
constexpr size_t OFF_CNT = 0;
constexpr size_t CNT_BYTES = 3ull * 32 * NB * 4;      // 196608
constexpr size_t OFF_SIGMA = CNT_BYTES;
constexpr size_t OFF_LOSS = OFF_SIGMA + 128;

// scaled = |x| * 128 where x = 2*detail; bin width = 1/256 in detail units
__device__ __forceinline__ void bump(unsigned* h, float scaled) {
    unsigned k = (unsigned)scaled;
    k = k < NB - 1 ? k : NB - 1;            // clamp tail into last bin (exact for loss)
    atomicAdd(&h[k], 1u);
}

__global__ __launch_bounds__(256) void k_zero(unsigned* __restrict__ cnt) {
    const int i = blockIdx.x * 256 + threadIdx.x;     // 12288 uint4 stores
    reinterpret_cast<uint4*>(cnt)[i] = make_uint4(0u, 0u, 0u, 0u);
}

// Fused 3-level Haar on disjoint 8x8 tiles; per-batch count histograms of
// |LH|,|HL|,|HH| at each level. src [32][1024][1024] f32.
__global__ __launch_bounds__(256, 4) void k_fused(
    const float* __restrict__ src, unsigned* __restrict__ gcnt)
{
    __shared__ unsigned h[3 * NB];                    // 6 KB
    for (int i = threadIdx.x; i < 3 * NB; i += 256) h[i] = 0u;
    __syncthreads();

    const int b = blockIdx.y;
    const int tI = blockIdx.x * 256 + threadIdx.x;    // 16384 tiles/batch
    const int ty = tI >> 7;                           // 128 tiles per row
    const int tx = tI & 127;
    const float* base = src + (size_t)b * 1048576 + (size_t)ty * 8192 + (size_t)tx * 8;

    // load full 8x8 tile: 16 independent float4 loads (deep memory ILP)
    float4 R[16];
    #pragma unroll
    for (int r = 0; r < 8; ++r) {
        R[2 * r]     = *reinterpret_cast<const float4*>(base + (size_t)r * 1024);
        R[2 * r + 1] = *reinterpret_cast<const float4*>(base + (size_t)r * 1024 + 4);
    }

    // level 1: 16 2x2 blocks -> ll1[4][4] + 48 details
    float ll1[16];
    #pragma unroll
    for (int i = 0; i < 4; ++i) {           // output row (input row-pair 2i,2i+1)
        #pragma unroll
        for (int j = 0; j < 2; ++j) {       // float4 part (cols 0-3 / 4-7)
            const float4 t = R[4 * i + j];
            const float4 u = R[4 * i + 2 + j];
            const float sab0 = t.x + t.y, dab0 = t.x - t.y;
            const float scd0 = u.x + u.y, dcd0 = u.x - u.y;
            ll1[4 * i + 2 * j] = 0.5f * (sab0 + scd0);
            bump(h, fabsf(sab0 - scd0) * BIN_SCALE);   // LH
            bump(h, fabsf(dab0 + dcd0) * BIN_SCALE);   // HL
            bump(h, fabsf(dab0 - dcd0) * BIN_SCALE);   // HH
            const float sab1 = t.z + t.w, dab1 = t.z - t.w;
            const float scd1 = u.z + u.w, dcd1 = u.z - u.w;
            ll1[4 * i + 2 * j + 1] = 0.5f * (sab1 + scd1);
            bump(h, fabsf(sab1 - scd1) * BIN_SCALE);
            bump(h, fabsf(dab1 + dcd1) * BIN_SCALE);
            bump(h, fabsf(dab1 - dcd1) * BIN_SCALE);
        }
    }

    // level 2: ll1 4x4 -> ll2[2][2] + 12 details
    float ll2[4];
    #pragma unroll
    for (int i = 0; i < 2; ++i) {
        #pragma unroll
        for (int j = 0; j < 2; ++j) {
            const float a = ll1[8 * i + 2 * j];
            const float bb = ll1[8 * i + 2 * j + 1];
            const float c = ll1[8 * i + 4 + 2 * j];
            const float d = ll1[8 * i + 4 + 2 * j + 1];
            const float sab = a + bb, dab = a - bb;
            const float scd = c + d, dcd = c - d;
            ll2[2 * i + j] = 0.5f * (sab + scd);
            bump(h + NB, fabsf(sab - scd) * BIN_SCALE);
            bump(h + NB, fabsf(dab + dcd) * BIN_SCALE);
            bump(h + NB, fabsf(dab - dcd) * BIN_SCALE);
        }
    }

    // level 3: ll2 2x2 -> 3 details
    {
        const float sab = ll2[0] + ll2[1], dab = ll2[0] - ll2[1];
        const float scd = ll2[2] + ll2[3], dcd = ll2[2] - ll2[3];
        bump(h + 2 * NB, fabsf(sab - scd) * BIN_SCALE);
        bump(h + 2 * NB, fabsf(dab + dcd) * BIN_SCALE);
        bump(h + 2 * NB, fabsf(dab - dcd) * BIN_SCALE);
    }

    __syncthreads();
    // merge into global [level][batch][NB]: 6 entries/thread
    for (int i = threadIdx.x; i < 3 * NB; i += 256) {
        const unsigned c = h[i];
        if (c) {
            const int lvl = i >> 9;           // i / NB
            const int bin = i & (NB - 1);
            atomicAdd(&gcnt[(size_t)lvl * 32 * NB + (size_t)b * NB + bin], c);
        }
    }
}

// sum of min(|x|, t) over one bin from count only (midpoint / uniform interp)
__device__ __forceinline__ float contrib(unsigned c, int k, float t) {
    if (!c) return 0.0f;
    const float lo = (float)k * BINW;
    if (t >= lo + BINW) return (float)c * (lo + 0.5f * BINW);
    if (t <= lo) return t * (float)c;
    const float f = (t - lo) * INV_BINW;
    const float below = f * (float)c;
    return below * 0.5f * (lo + t) + ((float)c - below) * t;
}

__global__ __launch_bounds__(256) void k_stats(
    const unsigned* __restrict__ cnt,
    float* __restrict__ sigma_arr, float* __restrict__ loss_arr)
{
    const int b = blockIdx.x;
    const int tid = threadIdx.x;
    const unsigned* c1 = cnt + (size_t)b * NB;
    const unsigned* c2 = cnt + (size_t)(32 + b) * NB;
    const unsigned* c3 = cnt + (size_t)(64 + b) * NB;

    __shared__ unsigned csum[256];              // 2-bin chunk sums of c1
    __shared__ float sh_t;
    csum[tid] = c1[2 * tid] + c1[2 * tid + 1];
    __syncthreads();

    if (tid == 0) {
        // N = 3*512*512 = 786432 even: median = avg of ranks 393216, 393217
        float vv[2];
        for (int q = 0; q < 2; ++q) {
            const long long r = 393216 + q;
            long long cum = 0;
            int ch = 0;
            while (ch < 255 && cum + (long long)csum[ch] < r) { cum += csum[ch]; ++ch; }
            int k = 2 * ch;
            if (cum + (long long)c1[k] < r) { cum += c1[k]; ++k; }
            const unsigned cc = c1[k];
            float frac = cc ? ((float)(r - cum) - 0.5f) / (float)cc : 0.5f;
            frac = fminf(fmaxf(frac, 0.0f), 1.0f);
            vv[q] = ((float)k + frac) * BINW;
        }
        const float med = 0.5f * (vv[0] + vv[1]);
        const float sg = med * (1.0f / 0.6745f);
        sigma_arr[b] = sg;
        sh_t = fminf(fmaxf(sg * 2.5f, 0.05f), 0.3f);   // clip(2.5σ, 0.05, 0.3)
    }
    __syncthreads();
    const float t = sh_t;

    constexpr float coef1 = 1.0f / (3.0f * 8388608.0f);   // 1/(3*1*B*512*512)
    constexpr float coef2 = 1.0f / (6.0f * 2097152.0f);   // 1/(3*2*B*256*256)
    constexpr float coef3 = 1.0f / (9.0f * 524288.0f);    // 1/(3*3*B*128*128)
    float part = 0.0f;
    #pragma unroll
    for (int rep = 0; rep < 2; ++rep) {
        const int i = tid + rep * 256;
        part += coef1 * contrib(c1[i], i, t);
        part += coef2 * contrib(c2[i], i, t * 0.5f);
        part += coef3 * contrib(c3[i], i, t * 0.25f);
    }
    for (int off = 32; off; off >>= 1) part += __shfl_down(part, off, 64);
    __shared__ float wred[4];
    if ((tid & 63) == 0) wred[tid >> 6] = part;
    __syncthreads();
    if (tid == 0) loss_arr[b] = wred[0] + wred[1] + wred[2] + wred[3];
}

__global__ void k_final(const float* __restrict__ sigma_arr,
                        const float* __restrict__ loss_arr,
                        float* __restrict__ out)
{
    if (threadIdx.x == 0 && blockIdx.x == 0) {
        float ls = 0.0f, ss = 0.0f;
        for (int i = 0; i < 32; ++i) { ls += loss_arr[i]; ss += sigma_arr[i]; }
        out[0] = ls;                  // total_loss
        out[1] = ss * (1.0f / 32.0f); // avg_noise
    }
}

} // namespace

extern "C" void kernel_launch(void* const* d_in, const int* in_sizes, int n_in,
                              void* d_out, int out_size, void* d_ws, size_t ws_size,
                              hipStream_t stream) {
    const float* pred = (const float*)d_in[0];   // [32,1,1024,1024] f32
    float* out = (float*)d_out;                  // [total_loss, avg_noise]
    char* ws = (char*)d_ws;

    unsigned* cnt = (unsigned*)(ws + OFF_CNT);
    float* sigma_arr = (float*)(ws + OFF_SIGMA);
    float* loss_arr = (float*)(ws + OFF_LOSS);

    // zero 192 KB of histograms: 12288 uint4 / 256 = 48 blocks
    k_zero<<<48, 256, 0, stream>>>(cnt);
    // fused 3-level DWT + histograms: 64 blocks x 32 batches, 1 tile/thread
    k_fused<<<dim3(64, 32), 256, 0, stream>>>(pred, cnt);
    // per-batch median -> sigma -> threshold -> loss
    k_stats<<<32, 256, 0, stream>>>(cnt, sigma_arr, loss_arr);
    // final scalars
    k_final<<<1, 64, 0, stream>>>(sigma_arr, loss_arr, out);
}

// Round 9
// 50.824 us; speedup vs baseline: 2.2438x; 1.0244x over previous
//
#include <hip/hip_runtime.h>

namespace {

constexpr int NB = 512;                     // bins cover [0, 2): binw = 1/256
constexpr float BIN_SCALE = 128.0f;         // bin = |2*detail| * 128 = |detail| * 256
constexpr float INV_BINW = 256.0f;
constexpr float BINW = 1.0f / 256.0f;

// ws layout: cnt [3 levels][32 batches][NB] u32 (192 KB)
constexpr size_t OFF_CNT = 0;

// scaled = |x| * 128 where x = 2*detail; bin width = 1/256 in detail units
__device__ __forceinline__ void bump(unsigned* h, float scaled) {
    unsigned k = (unsigned)scaled;
    k = k < NB - 1 ? k : NB - 1;            // clamp tail into last bin (exact for loss)
    atomicAdd(&h[k], 1u);
}

__global__ __launch_bounds__(256) void k_zero(unsigned* __restrict__ cnt,
                                              float* __restrict__ out) {
    const int i = blockIdx.x * 256 + threadIdx.x;     // 12288 uint4 stores
    reinterpret_cast<uint4*>(cnt)[i] = make_uint4(0u, 0u, 0u, 0u);
    if (i == 0) { out[0] = 0.0f; out[1] = 0.0f; }
}

// Fused 3-level Haar on disjoint 8x8 tiles; per-batch count histograms of
// |LH|,|HL|,|HH| at each level. src [32][1024][1024] f32.
// Two wave-pair-private histogram copies to halve LDS atomic conflicts.
__global__ __launch_bounds__(256, 4) void k_fused(
    const float* __restrict__ src, unsigned* __restrict__ gcnt)
{
    __shared__ unsigned h[2][3 * NB];                 // 12 KB
    for (int i = threadIdx.x; i < 2 * 3 * NB; i += 256)
        (&h[0][0])[i] = 0u;
    __syncthreads();

    unsigned* hw = h[(threadIdx.x >> 6) & 1];         // waves 0,2 -> copy0; 1,3 -> copy1

    const int b = blockIdx.y;
    const int tI = blockIdx.x * 256 + threadIdx.x;    // 16384 tiles/batch
    const int ty = tI >> 7;                           // 128 tiles per row
    const int tx = tI & 127;
    const float* base = src + (size_t)b * 1048576 + (size_t)ty * 8192 + (size_t)tx * 8;

    // load full 8x8 tile: 16 independent float4 loads (deep memory ILP)
    float4 R[16];
    #pragma unroll
    for (int r = 0; r < 8; ++r) {
        R[2 * r]     = *reinterpret_cast<const float4*>(base + (size_t)r * 1024);
        R[2 * r + 1] = *reinterpret_cast<const float4*>(base + (size_t)r * 1024 + 4);
    }

    // level 1: 16 2x2 blocks -> ll1[4][4] + 48 details
    float ll1[16];
    #pragma unroll
    for (int i = 0; i < 4; ++i) {           // output row (input row-pair 2i,2i+1)
        #pragma unroll
        for (int j = 0; j < 2; ++j) {       // float4 part (cols 0-3 / 4-7)
            const float4 t = R[4 * i + j];
            const float4 u = R[4 * i + 2 + j];
            const float sab0 = t.x + t.y, dab0 = t.x - t.y;
            const float scd0 = u.x + u.y, dcd0 = u.x - u.y;
            ll1[4 * i + 2 * j] = 0.5f * (sab0 + scd0);
            bump(hw, fabsf(sab0 - scd0) * BIN_SCALE);   // LH
            bump(hw, fabsf(dab0 + dcd0) * BIN_SCALE);   // HL
            bump(hw, fabsf(dab0 - dcd0) * BIN_SCALE);   // HH
            const float sab1 = t.z + t.w, dab1 = t.z - t.w;
            const float scd1 = u.z + u.w, dcd1 = u.z - u.w;
            ll1[4 * i + 2 * j + 1] = 0.5f * (sab1 + scd1);
            bump(hw, fabsf(sab1 - scd1) * BIN_SCALE);
            bump(hw, fabsf(dab1 + dcd1) * BIN_SCALE);
            bump(hw, fabsf(dab1 - dcd1) * BIN_SCALE);
        }
    }

    // level 2: ll1 4x4 -> ll2[2][2] + 12 details
    float ll2[4];
    #pragma unroll
    for (int i = 0; i < 2; ++i) {
        #pragma unroll
        for (int j = 0; j < 2; ++j) {
            const float a = ll1[8 * i + 2 * j];
            const float bb = ll1[8 * i + 2 * j + 1];
            const float c = ll1[8 * i + 4 + 2 * j];
            const float d = ll1[8 * i + 4 + 2 * j + 1];
            const float sab = a + bb, dab = a - bb;
            const float scd = c + d, dcd = c - d;
            ll2[2 * i + j] = 0.5f * (sab + scd);
            bump(hw + NB, fabsf(sab - scd) * BIN_SCALE);
            bump(hw + NB, fabsf(dab + dcd) * BIN_SCALE);
            bump(hw + NB, fabsf(dab - dcd) * BIN_SCALE);
        }
    }

    // level 3: ll2 2x2 -> 3 details
    {
        const float sab = ll2[0] + ll2[1], dab = ll2[0] - ll2[1];
        const float scd = ll2[2] + ll2[3], dcd = ll2[2] - ll2[3];
        bump(hw + 2 * NB, fabsf(sab - scd) * BIN_SCALE);
        bump(hw + 2 * NB, fabsf(dab + dcd) * BIN_SCALE);
        bump(hw + 2 * NB, fabsf(dab - dcd) * BIN_SCALE);
    }

    __syncthreads();
    // merge the two copies into global [level][batch][NB]: 6 entries/thread
    for (int i = threadIdx.x; i < 3 * NB; i += 256) {
        const unsigned c = h[0][i] + h[1][i];
        if (c) {
            const int lvl = i >> 9;           // i / NB
            const int bin = i & (NB - 1);
            atomicAdd(&gcnt[(size_t)lvl * 32 * NB + (size_t)b * NB + bin], c);
        }
    }
}

// sum of min(|x|, t) over one bin from count only (midpoint / uniform interp)
__device__ __forceinline__ float contrib(unsigned c, int k, float t) {
    if (!c) return 0.0f;
    const float lo = (float)k * BINW;
    if (t >= lo + BINW) return (float)c * (lo + 0.5f * BINW);
    if (t <= lo) return t * (float)c;
    const float f = (t - lo) * INV_BINW;
    const float below = f * (float)c;
    return below * 0.5f * (lo + t) + ((float)c - below) * t;
}

// Per-batch: median (rank-select) -> sigma -> threshold -> loss; then
// accumulate the two output scalars with device atomics (zeroed by k_zero).
__global__ __launch_bounds__(256) void k_stats(
    const unsigned* __restrict__ cnt, float* __restrict__ out)
{
    const int b = blockIdx.x;
    const int tid = threadIdx.x;
    const unsigned* c1 = cnt + (size_t)b * NB;
    const unsigned* c2 = cnt + (size_t)(32 + b) * NB;
    const unsigned* c3 = cnt + (size_t)(64 + b) * NB;

    __shared__ unsigned csum[256];              // 2-bin chunk sums of c1
    __shared__ float sh_t, sh_sigma;
    csum[tid] = c1[2 * tid] + c1[2 * tid + 1];
    __syncthreads();

    if (tid == 0) {
        // N = 3*512*512 = 786432 even: median = avg of ranks 393216, 393217
        float vv[2];
        for (int q = 0; q < 2; ++q) {
            const long long r = 393216 + q;
            long long cum = 0;
            int ch = 0;
            while (ch < 255 && cum + (long long)csum[ch] < r) { cum += csum[ch]; ++ch; }
            int k = 2 * ch;
            if (cum + (long long)c1[k] < r) { cum += c1[k]; ++k; }
            const unsigned cc = c1[k];
            float frac = cc ? ((float)(r - cum) - 0.5f) / (float)cc : 0.5f;
            frac = fminf(fmaxf(frac, 0.0f), 1.0f);
            vv[q] = ((float)k + frac) * BINW;
        }
        const float med = 0.5f * (vv[0] + vv[1]);
        const float sg = med * (1.0f / 0.6745f);
        sh_sigma = sg;
        sh_t = fminf(fmaxf(sg * 2.5f, 0.05f), 0.3f);   // clip(2.5σ, 0.05, 0.3)
    }
    __syncthreads();
    const float t = sh_t;

    constexpr float coef1 = 1.0f / (3.0f * 8388608.0f);   // 1/(3*1*B*512*512)
    constexpr float coef2 = 1.0f / (6.0f * 2097152.0f);   // 1/(3*2*B*256*256)
    constexpr float coef3 = 1.0f / (9.0f * 524288.0f);    // 1/(3*3*B*128*128)
    float part = 0.0f;
    #pragma unroll
    for (int rep = 0; rep < 2; ++rep) {
        const int i = tid + rep * 256;
        part += coef1 * contrib(c1[i], i, t);
        part += coef2 * contrib(c2[i], i, t * 0.5f);
        part += coef3 * contrib(c3[i], i, t * 0.25f);
    }
    for (int off = 32; off; off >>= 1) part += __shfl_down(part, off, 64);
    __shared__ float wred[4];
    if ((tid & 63) == 0) wred[tid >> 6] = part;
    __syncthreads();
    if (tid == 0) {
        atomicAdd(&out[0], wred[0] + wred[1] + wred[2] + wred[3]);  // total_loss
        atomicAdd(&out[1], sh_sigma * (1.0f / 32.0f));              // avg_noise
    }
}

} // namespace

extern "C" void kernel_launch(void* const* d_in, const int* in_sizes, int n_in,
                              void* d_out, int out_size, void* d_ws, size_t ws_size,
                              hipStream_t stream) {
    const float* pred = (const float*)d_in[0];   // [32,1,1024,1024] f32
    float* out = (float*)d_out;                  // [total_loss, avg_noise]
    char* ws = (char*)d_ws;

    unsigned* cnt = (unsigned*)(ws + OFF_CNT);

    // zero 192 KB of histograms + the 2 output scalars: 12288 uint4 / 256 = 48 blocks
    k_zero<<<48, 256, 0, stream>>>(cnt, out);
    // fused 3-level DWT + histograms: 64 blocks x 32 batches, 1 tile/thread
    k_fused<<<dim3(64, 32), 256, 0, stream>>>(pred, cnt);
    // per-batch median -> sigma -> threshold -> loss -> atomic accumulate scalars
    k_stats<<<32, 256, 0, stream>>>(cnt, out);
}

// Round 10
// 40.947 us; speedup vs baseline: 2.7851x; 1.2412x over previous
//
#include <hip/hip_runtime.h>

namespace {

constexpr int NB = 512;                     // bins cover [0, 2): binw = 1/256
constexpr float BIN_SCALE = 128.0f;         // bin = |2*detail| * 128 = |detail| * 256
constexpr float INV_BINW = 256.0f;
constexpr float BINW = 1.0f / 256.0f;

constexpr size_t OFF_CNT = 0;               // cnt [3][32][NB] u32 (192 KB)

__device__ __forceinline__ void bump(unsigned* h, float scaled) {
    unsigned k = (unsigned)scaled;
    k = k < NB - 1 ? k : NB - 1;            // clamp tail into last bin (exact for loss)
    atomicAdd(&h[k], 1u);
}

__global__ __launch_bounds__(256) void k_zero(unsigned* __restrict__ cnt,
                                              float* __restrict__ out) {
    const int i = blockIdx.x * 256 + threadIdx.x;     // 12288 uint4 stores
    reinterpret_cast<uint4*>(cnt)[i] = make_uint4(0u, 0u, 0u, 0u);
    if (i == 0) { out[0] = 0.0f; out[1] = 0.0f; }
}

// Fused 3-level Haar on disjoint 8x8 tiles; per-batch count histograms of
// |LH|,|HL|,|HH| at each level. src [32][1024][1024] f32.
__global__ __launch_bounds__(256, 4) void k_fused(
    const float* __restrict__ src, unsigned* __restrict__ gcnt)
{
    __shared__ unsigned h[2][3 * NB];                 // 12 KB, wave-pair copies
    for (int i = threadIdx.x; i < 2 * 3 * NB; i += 256)
        (&h[0][0])[i] = 0u;
    __syncthreads();

    unsigned* hw = h[(threadIdx.x >> 6) & 1];

    const int b = blockIdx.y;
    const int tI = blockIdx.x * 256 + threadIdx.x;    // 16384 tiles/batch
    const int ty = tI >> 7;
    const int tx = tI & 127;
    const float* base = src + (size_t)b * 1048576 + (size_t)ty * 8192 + (size_t)tx * 8;

    float4 R[16];
    #pragma unroll
    for (int r = 0; r < 8; ++r) {
        R[2 * r]     = *reinterpret_cast<const float4*>(base + (size_t)r * 1024);
        R[2 * r + 1] = *reinterpret_cast<const float4*>(base + (size_t)r * 1024 + 4);
    }

    // level 1: 16 2x2 blocks -> ll1[4][4] + 48 details
    float ll1[16];
    #pragma unroll
    for (int i = 0; i < 4; ++i) {
        #pragma unroll
        for (int j = 0; j < 2; ++j) {
            const float4 t = R[4 * i + j];
            const float4 u = R[4 * i + 2 + j];
            const float sab0 = t.x + t.y, dab0 = t.x - t.y;
            const float scd0 = u.x + u.y, dcd0 = u.x - u.y;
            ll1[4 * i + 2 * j] = 0.5f * (sab0 + scd0);
            bump(hw, fabsf(sab0 - scd0) * BIN_SCALE);   // LH
            bump(hw, fabsf(dab0 + dcd0) * BIN_SCALE);   // HL
            bump(hw, fabsf(dab0 - dcd0) * BIN_SCALE);   // HH
            const float sab1 = t.z + t.w, dab1 = t.z - t.w;
            const float scd1 = u.z + u.w, dcd1 = u.z - u.w;
            ll1[4 * i + 2 * j + 1] = 0.5f * (sab1 + scd1);
            bump(hw, fabsf(sab1 - scd1) * BIN_SCALE);
            bump(hw, fabsf(dab1 + dcd1) * BIN_SCALE);
            bump(hw, fabsf(dab1 - dcd1) * BIN_SCALE);
        }
    }

    // level 2
    float ll2[4];
    #pragma unroll
    for (int i = 0; i < 2; ++i) {
        #pragma unroll
        for (int j = 0; j < 2; ++j) {
            const float a = ll1[8 * i + 2 * j];
            const float bb = ll1[8 * i + 2 * j + 1];
            const float c = ll1[8 * i + 4 + 2 * j];
            const float d = ll1[8 * i + 4 + 2 * j + 1];
            const float sab = a + bb, dab = a - bb;
            const float scd = c + d, dcd = c - d;
            ll2[2 * i + j] = 0.5f * (sab + scd);
            bump(hw + NB, fabsf(sab - scd) * BIN_SCALE);
            bump(hw + NB, fabsf(dab + dcd) * BIN_SCALE);
            bump(hw + NB, fabsf(dab - dcd) * BIN_SCALE);
        }
    }

    // level 3
    {
        const float sab = ll2[0] + ll2[1], dab = ll2[0] - ll2[1];
        const float scd = ll2[2] + ll2[3], dcd = ll2[2] - ll2[3];
        bump(hw + 2 * NB, fabsf(sab - scd) * BIN_SCALE);
        bump(hw + 2 * NB, fabsf(dab + dcd) * BIN_SCALE);
        bump(hw + 2 * NB, fabsf(dab - dcd) * BIN_SCALE);
    }

    __syncthreads();
    for (int i = threadIdx.x; i < 3 * NB; i += 256) {
        const unsigned c = h[0][i] + h[1][i];
        if (c) {
            const int lvl = i >> 9;
            const int bin = i & (NB - 1);
            atomicAdd(&gcnt[(size_t)lvl * 32 * NB + (size_t)b * NB + bin], c);
        }
    }
}

// sum of min(|x|, t) over one bin from count only (midpoint / uniform interp)
__device__ __forceinline__ float contrib(unsigned c, int k, float t) {
    if (!c) return 0.0f;
    const float lo = (float)k * BINW;
    if (t >= lo + BINW) return (float)c * (lo + 0.5f * BINW);
    if (t <= lo) return t * (float)c;
    const float f = (t - lo) * INV_BINW;
    const float below = f * (float)c;
    return below * 0.5f * (lo + t) + ((float)c - below) * t;
}

// Per-batch: parallel-scan median -> sigma -> threshold -> loss -> atomic scalars.
__global__ __launch_bounds__(256) void k_stats(
    const unsigned* __restrict__ cnt, float* __restrict__ out)
{
    const int b = blockIdx.x;
    const int tid = threadIdx.x;
    const int lane = tid & 63;
    const int wv = tid >> 6;
    const unsigned* c1 = cnt + (size_t)b * NB;
    const unsigned* c2 = cnt + (size_t)(32 + b) * NB;
    const unsigned* c3 = cnt + (size_t)(64 + b) * NB;

    // --- parallel rank-select median on c1 (2 bins per thread) ---
    const unsigned e0 = c1[2 * tid], e1 = c1[2 * tid + 1];
    unsigned v = e0 + e1;
    // wave-inclusive scan (shfl_up, width 64)
    #pragma unroll
    for (int off = 1; off < 64; off <<= 1) {
        const unsigned n = __shfl_up(v, off, 64);
        if (lane >= off) v += n;
    }
    __shared__ unsigned wsum[4];
    if (lane == 63) wsum[wv] = v;
    __syncthreads();
    unsigned wpre = 0;
    #pragma unroll
    for (int w = 0; w < 4; ++w) wpre += (w < wv) ? wsum[w] : 0u;
    const unsigned incl = v + wpre;                 // inclusive prefix over chunks
    const unsigned excl = incl - (e0 + e1);         // exclusive prefix

    __shared__ int sh_k[2];
    __shared__ unsigned sh_cum[2];
    __shared__ float sh_t, sh_sigma;
    #pragma unroll
    for (int q = 0; q < 2; ++q) {
        const unsigned r = 393216u + q;             // N = 786432, ranks N/2, N/2+1
        if (excl < r && r <= incl) {                // rank lands in my 2-bin chunk
            int k = 2 * tid;
            unsigned cum = excl;
            if (cum + e0 < r) { cum += e0; ++k; }
            sh_k[q] = k;
            sh_cum[q] = cum;
        }
    }
    __syncthreads();

    if (tid == 0) {
        float vv[2];
        #pragma unroll
        for (int q = 0; q < 2; ++q) {
            const unsigned r = 393216u + q;
            const int k = sh_k[q];
            const unsigned cc = c1[k];
            float frac = cc ? ((float)(r - sh_cum[q]) - 0.5f) / (float)cc : 0.5f;
            frac = fminf(fmaxf(frac, 0.0f), 1.0f);
            vv[q] = ((float)k + frac) * BINW;
        }
        const float med = 0.5f * (vv[0] + vv[1]);
        const float sg = med * (1.0f / 0.6745f);
        sh_sigma = sg;
        sh_t = fminf(fmaxf(sg * 2.5f, 0.05f), 0.3f);   // clip(2.5σ, 0.05, 0.3)
    }
    __syncthreads();
    const float t = sh_t;

    constexpr float coef1 = 1.0f / (3.0f * 8388608.0f);   // 1/(3*1*B*512*512)
    constexpr float coef2 = 1.0f / (6.0f * 2097152.0f);   // 1/(3*2*B*256*256)
    constexpr float coef3 = 1.0f / (9.0f * 524288.0f);    // 1/(3*3*B*128*128)
    float part = 0.0f;
    #pragma unroll
    for (int rep = 0; rep < 2; ++rep) {
        const int i = tid + rep * 256;
        part += coef1 * contrib(c1[i], i, t);
        part += coef2 * contrib(c2[i], i, t * 0.5f);
        part += coef3 * contrib(c3[i], i, t * 0.25f);
    }
    for (int off = 32; off; off >>= 1) part += __shfl_down(part, off, 64);
    __shared__ float wred[4];
    if ((tid & 63) == 0) wred[tid >> 6] = part;
    __syncthreads();
    if (tid == 0) {
        atomicAdd(&out[0], wred[0] + wred[1] + wred[2] + wred[3]);  // total_loss
        atomicAdd(&out[1], sh_sigma * (1.0f / 32.0f));              // avg_noise
    }
}

} // namespace

extern "C" void kernel_launch(void* const* d_in, const int* in_sizes, int n_in,
                              void* d_out, int out_size, void* d_ws, size_t ws_size,
                              hipStream_t stream) {
    const float* pred = (const float*)d_in[0];   // [32,1,1024,1024] f32
    float* out = (float*)d_out;                  // [total_loss, avg_noise]
    char* ws = (char*)d_ws;

    unsigned* cnt = (unsigned*)(ws + OFF_CNT);

    k_zero<<<48, 256, 0, stream>>>(cnt, out);
    k_fused<<<dim3(64, 32), 256, 0, stream>>>(pred, cnt);
    k_stats<<<32, 256, 0, stream>>>(cnt, out);
}